// Round 5
// baseline (162.870 us; speedup 1.0000x reference)
//
#include <hip/hip_runtime.h>

// B=64, S=512, D=768 fp32.
// out = concat( hidden[:,0,:] (64*768), segment-mean by sent_id (64*20*768) )
//
// Main kernel: grid (64 b, 3 dc, 4 sc) = 768 blocks x 256 thr (4 waves).
// Block = one (batch, 256-float col chunk, 128-row S-chunk). Counting-sort the
// chunk's rows by sid; sorted segmented sum in registers (P=8 float4 ring, no
// fp atomics in the hot path); partial sums -> d_ws. Reduce kernel sums the 4
// S-chunk partials, divides by count, writes sent_reps. Deterministic; avoids
// HIP's shared-float atomicAdd CAS-loop lowering in all hot paths.

constexpr int B_  = 64;
constexpr int S_  = 512;
constexpr int D_  = 768;
constexpr int M1  = 21;    // sid in [0,20]
constexpr int MS  = 20;    // segments emitted
constexpr int CF  = 256;   // floats per column chunk (64 lanes x 4)
constexpr int NC  = 3;     // D / CF
constexpr int NSC = 4;     // S chunks
constexpr int SC  = S_ / NSC;  // 128 rows per chunk
constexpr int NT  = 256;   // threads per block = 4 waves
constexpr int NW  = 4;     // waves per block
constexpr int RPW = SC / NW;   // 32 sorted positions per wave
constexpr int P   = 8;     // prefetch depth

// ws layout: partial[b][sc][seg][d]  (B*NSC*MS*D floats), then cntf[b][seg]
constexpr size_t WS_PART = (size_t)B_ * NSC * MS * D_;

__global__ __launch_bounds__(NT, 3)
void aspire_main(const float* __restrict__ hidden,
                 const int* __restrict__ sent_ids,
                 float* __restrict__ out,
                 float* __restrict__ ws) {
    __shared__ float acc[M1 * CF];   // 21504 B
    __shared__ int   sids[S_];
    __shared__ int   cnt[M1];        // full-S histogram
    __shared__ int   ccnt[M1];       // chunk histogram
    __shared__ int   coffs[M1];
    __shared__ short ord[SC];        // chunk-local row, sorted by sid
    __shared__ short ssid[SC];

    const int b    = blockIdx.x;
    const int dc   = blockIdx.y;
    const int sc   = blockIdx.z;
    const int tid  = threadIdx.x;    // 0..255
    const int lane = tid & 63;
    const int w    = tid >> 6;       // 0..3

    // ---- init ----
    for (int i = tid; i < M1 * CF; i += NT) acc[i] = 0.0f;
    if (tid < M1) { cnt[tid] = 0; ccnt[tid] = 0; }
    __syncthreads();

    // full-S sids + histogram (int LDS atomics: native ds_add_u32)
    for (int i = tid; i < S_; i += NT) {
        int sv = sent_ids[b * S_ + i];
        sids[i] = sv;
        atomicAdd(&cnt[sv], 1);
    }
    __syncthreads();

    // chunk histogram + prefix + scatter (counting sort of 128 rows)
    if (tid < SC) atomicAdd(&ccnt[sids[sc * SC + tid]], 1);
    __syncthreads();
    if (tid == 0) {
        int r = 0;
        for (int k = 0; k < M1; ++k) { coffs[k] = r; r += ccnt[k]; }
    }
    __syncthreads();
    if (tid < SC) {
        int sv  = sids[sc * SC + tid];
        int pos = atomicAdd(&coffs[sv], 1);
        ord[pos]  = (short)tid;      // chunk-local row index
        ssid[pos] = (short)sv;
    }
    // doc_cls_reps = hidden[:,0,:] (one S-chunk's blocks write it)
    if (sc == 0) {
        out[b * D_ + dc * CF + tid] = hidden[(size_t)b * S_ * D_ + dc * CF + tid];
    }
    __syncthreads();

    // ---- hot loop: sorted segmented sum over this chunk ----
    const float* hb = hidden + ((size_t)b * S_ + sc * SC) * D_ + dc * CF + 4 * lane;
    const int p0 = w * RPW;

    float4 buf[P];
    #pragma unroll
    for (int j = 0; j < P; ++j) {
        int s = ord[p0 + j];
        buf[j] = *(const float4*)(hb + (size_t)s * D_);
    }

    float sx = 0.0f, sy = 0.0f, sz = 0.0f, sw = 0.0f;
    int cur = ssid[p0];

    #pragma unroll 1
    for (int t0 = 0; t0 < RPW - P; t0 += P) {
        #pragma unroll
        for (int j = 0; j < P; ++j) {
            int t   = t0 + j;
            int sid = ssid[p0 + t];           // wave-uniform
            if (sid != cur) {                 // rare scalar branch
                float* a = &acc[cur * CF + 4 * lane];
                atomicAdd(a + 0, sx); atomicAdd(a + 1, sy);
                atomicAdd(a + 2, sz); atomicAdd(a + 3, sw);
                sx = sy = sz = sw = 0.0f;
                cur = sid;
            }
            float4 v = buf[j];
            sx += v.x; sy += v.y; sz += v.z; sw += v.w;
            int sn = ord[p0 + t + P];         // refill (independent)
            buf[j] = *(const float4*)(hb + (size_t)sn * D_);
        }
    }
    #pragma unroll
    for (int j = 0; j < P; ++j) {             // tail: consume only
        int t   = RPW - P + j;
        int sid = ssid[p0 + t];
        if (sid != cur) {
            float* a = &acc[cur * CF + 4 * lane];
            atomicAdd(a + 0, sx); atomicAdd(a + 1, sy);
            atomicAdd(a + 2, sz); atomicAdd(a + 3, sw);
            sx = sy = sz = sw = 0.0f;
            cur = sid;
        }
        float4 v = buf[j];
        sx += v.x; sy += v.y; sz += v.z; sw += v.w;
    }
    {
        float* a = &acc[cur * CF + 4 * lane];
        atomicAdd(a + 0, sx); atomicAdd(a + 1, sy);
        atomicAdd(a + 2, sz); atomicAdd(a + 3, sw);
    }
    __syncthreads();

    // ---- write partial sums (coalesced, no atomics) ----
    // partial[(b*NSC+sc)][seg][dc*CF+col]
    for (int f = tid; f < MS * CF; f += NT) {
        int seg = f >> 8;            // f / CF
        int col = f & (CF - 1);
        ws[((size_t)(b * NSC + sc) * MS + seg) * D_ + dc * CF + col] =
            acc[seg * CF + col];
    }
    // counts (once per batch)
    if (dc == 0 && sc == 0 && tid < MS) {
        ws[WS_PART + b * MS + tid] = (float)cnt[tid];
    }
}

__global__ __launch_bounds__(NT)
void aspire_reduce(const float* __restrict__ ws, float* __restrict__ out) {
    // B*MS*D floats = 983040 = 245760 float4; grid covers exactly.
    int i = blockIdx.x * NT + threadIdx.x;
    if (i >= (B_ * MS * D_) / 4) return;
    int e0   = i * 4;
    int bseg = e0 / D_;               // b*MS + seg
    int d    = e0 - bseg * D_;
    int b    = bseg / MS;
    int seg  = bseg - b * MS;

    float4 s = {0.f, 0.f, 0.f, 0.f};
    #pragma unroll
    for (int scn = 0; scn < NSC; ++scn) {
        const float4 p = *(const float4*)
            (ws + ((size_t)(b * NSC + scn) * MS + seg) * D_ + d);
        s.x += p.x; s.y += p.y; s.z += p.z; s.w += p.w;
    }
    float ct = ws[WS_PART + bseg];
    ct = ct < 1.0f ? 1.0f : ct;
    float inv = 1.0f / ct;
    float4 r = {s.x * inv, s.y * inv, s.z * inv, s.w * inv};
    *(float4*)(out + (size_t)B_ * D_ + e0) = r;
}

extern "C" void kernel_launch(void* const* d_in, const int* in_sizes, int n_in,
                              void* d_out, int out_size, void* d_ws, size_t ws_size,
                              hipStream_t stream) {
    const float* hidden   = (const float*)d_in[0];
    const int*   sent_ids = (const int*)d_in[1];
    float* out = (float*)d_out;
    float* ws  = (float*)d_ws;

    dim3 grid(B_, NC, NSC);          // (64, 3, 4) = 768 blocks
    aspire_main<<<grid, NT, 0, stream>>>(hidden, sent_ids, out, ws);

    int n4 = (B_ * MS * D_) / 4;     // 245760
    aspire_reduce<<<n4 / NT, NT, 0, stream>>>(ws, out);
}